// Round 3
// baseline (213.047 us; speedup 1.0000x reference)
//
#include <hip/hip_runtime.h>

// Adaptive average pooling (16, 512, 512, 64) f32 -> (16, 7, 7, 64) f32.
// One block per (b, oh, ow, h-chunk): fully-contiguous window reads,
// LDS reduce, 256B partial per block; tiny finisher kernel sums 4 partials.
// Windows: start(o) = (o*IN)/OUT, stop(o) = ((o+1)*IN + OUT-1)/OUT (all 74 wide).

#define IN_HW  512
#define OUT_HW 7
#define NB     16
#define NC     64
#define C4     16      // float4 groups per spatial position (64 ch / 4)
#define HCHUNKS 4      // h-chunks per output pixel
#define NPIX   (NB * OUT_HW * OUT_HW)   // 784

__device__ __forceinline__ int win_start(int o) { return (o * IN_HW) / OUT_HW; }
__device__ __forceinline__ int win_stop(int o)  { return ((o + 1) * IN_HW + OUT_HW - 1) / OUT_HW; }

// ---------------- pass 1: windowed partial sums ----------------
// grid.x = NPIX * HCHUNKS (3136), block = 256
// partial[blk*16 + c4] = sum over (h in chunk, w in window) of x[b,h,w,c4]
__global__ __launch_bounds__(256)
void pool_partial_kernel(const float4* __restrict__ x, float4* __restrict__ partial) {
    __shared__ float4 red[256];

    const int blk = blockIdx.x;
    const int hc  = blk & (HCHUNKS - 1);
    const int pix = blk >> 2;                 // (b*7 + oh)*7 + ow
    const int ow  = pix % OUT_HW;
    const int oh  = (pix / OUT_HW) % OUT_HW;
    const int b   = pix / (OUT_HW * OUT_HW);

    const int hs = win_start(oh), he = win_stop(oh);
    const int nh = he - hs;
    const int r0 = hs + (hc * nh) / HCHUNKS;
    const int r1 = hs + ((hc + 1) * nh) / HCHUNKS;

    const int ws = win_start(ow), we = win_stop(ow);
    const int span = (we - ws) * C4;          // 1184 float4 per row segment

    const int tid = threadIdx.x;

    float4 acc = make_float4(0.f, 0.f, 0.f, 0.f);
    #pragma unroll 2
    for (int h = r0; h < r1; ++h) {
        const float4* seg = x + ((size_t)(b * IN_HW + h) * IN_HW + ws) * C4;
        #pragma unroll 5
        for (int j = tid; j < span; j += 256) {
            float4 v = seg[j];
            acc.x += v.x; acc.y += v.y; acc.z += v.z; acc.w += v.w;
        }
    }
    red[tid] = acc;
    __syncthreads();

    // tree reduce: thread i (<16) ends with sum over threads {i, i+16, ..., i+240},
    // all of which have c4 = i (256 % 16 == 0 and segments are 16-aligned).
    #pragma unroll
    for (int s = 128; s >= 16; s >>= 1) {
        if (tid < s) {
            float4 o = red[tid + s];
            float4 m = red[tid];
            m.x += o.x; m.y += o.y; m.z += o.z; m.w += o.w;
            red[tid] = m;
        }
        __syncthreads();
    }

    if (tid < C4) {
        partial[(size_t)blk * C4 + tid] = red[tid];
    }
}

// ---------------- pass 2: sum 4 partials + scale ----------------
// total threads = NPIX * C4 = 12544; 49 blocks x 256
__global__ __launch_bounds__(256)
void pool_finish_kernel(const float4* __restrict__ partial, float4* __restrict__ out) {
    const int idx = blockIdx.x * 256 + threadIdx.x;
    if (idx >= NPIX * C4) return;

    const int c4  = idx & (C4 - 1);
    const int pix = idx >> 4;
    const int ow  = pix % OUT_HW;
    const int oh  = (pix / OUT_HW) % OUT_HW;

    float4 acc = make_float4(0.f, 0.f, 0.f, 0.f);
    #pragma unroll
    for (int k = 0; k < HCHUNKS; ++k) {
        float4 v = partial[((size_t)pix * HCHUNKS + k) * C4 + c4];
        acc.x += v.x; acc.y += v.y; acc.z += v.z; acc.w += v.w;
    }
    const float scale = 1.0f / (float)((win_stop(oh) - win_start(oh)) *
                                       (win_stop(ow) - win_start(ow)));
    acc.x *= scale; acc.y *= scale; acc.z *= scale; acc.w *= scale;
    out[idx] = acc;
}

// ---------------- fallback: fused single kernel (if ws too small) ----------------
__global__ __launch_bounds__(256)
void pool_fused_kernel(const float4* __restrict__ x, float4* __restrict__ out) {
    __shared__ float4 red[256];

    const int blk = blockIdx.x;              // (b*7 + oh)*7 + ow
    const int ow = blk % OUT_HW;
    const int oh = (blk / OUT_HW) % OUT_HW;
    const int b  = blk / (OUT_HW * OUT_HW);

    const int tid = threadIdx.x;
    const int c4 = tid & 15;
    const int rg = tid >> 4;

    const int hs = win_start(oh), he = win_stop(oh);
    const int ws = win_start(ow), we = win_stop(ow);

    float4 acc = make_float4(0.f, 0.f, 0.f, 0.f);
    for (int h = hs + rg; h < he; h += 16) {
        const float4* row = x + ((size_t)(b * IN_HW + h)) * (IN_HW * C4);
        #pragma unroll 8
        for (int w = ws; w < we; ++w) {
            float4 v = row[w * C4 + c4];
            acc.x += v.x; acc.y += v.y; acc.z += v.z; acc.w += v.w;
        }
    }
    red[tid] = acc;
    __syncthreads();

    #pragma unroll
    for (int s = 8; s >= 1; s >>= 1) {
        if (rg < s) {
            float4 o = red[(rg + s) * 16 + c4];
            float4 m = red[rg * 16 + c4];
            m.x += o.x; m.y += o.y; m.z += o.z; m.w += o.w;
            red[rg * 16 + c4] = m;
        }
        __syncthreads();
    }

    if (rg == 0) {
        const float scale = 1.0f / (float)((he - hs) * (we - ws));
        float4 m = red[c4];
        m.x *= scale; m.y *= scale; m.z *= scale; m.w *= scale;
        out[(size_t)blk * C4 + c4] = m;
    }
}

extern "C" void kernel_launch(void* const* d_in, const int* in_sizes, int n_in,
                              void* d_out, int out_size, void* d_ws, size_t ws_size,
                              hipStream_t stream) {
    const float4* x = (const float4*)d_in[0];
    float4* out = (float4*)d_out;

    const size_t ws_needed = (size_t)NPIX * HCHUNKS * C4 * sizeof(float4); // ~800 KB

    if (ws_size >= ws_needed) {
        float4* partial = (float4*)d_ws;
        pool_partial_kernel<<<NPIX * HCHUNKS, 256, 0, stream>>>(x, partial);
        pool_finish_kernel<<<(NPIX * C4 + 255) / 256, 256, 0, stream>>>(partial, out);
    } else {
        pool_fused_kernel<<<NPIX, 256, 0, stream>>>(x, out);
    }
}

// Round 4
// 194.421 us; speedup vs baseline: 1.0958x; 1.0958x over previous
//
#include <hip/hip_runtime.h>

// Adaptive average pooling (16, 512, 512, 64) f32 -> (16, 7, 7, 64) f32.
// All 49 windows are 74x74 (overlapping by 1 row/col with neighbors).
//
// pool_stream: one block per (b, oh, 4-row chunk). Block streams its rows
// FULLY SEQUENTIALLY (thread tid reads float4 tid+256j; c4=tid&15 invariant,
// w = (tid>>4)+16j). For compile-time j the target window index is a
// compile-time constant except at 6 j's, where a 16-lane-uniform predicate
// on base=tid>>4 selects K vs K+1 (boundary lane adds to both -- the 1-col
// window overlap). Register acc[7], static indices only. LDS-reduce over the
// 16 base groups -> 7x16 float4 partial per block. Tiny finisher sums chunks.

#define IN_HW  512
#define OUT_HW 7
#define NB     16
#define C4     16
#define RPC    4                    // rows per chunk
#define NCHUNK 19                   // ceil(74 / RPC)
#define NPAIR  (NB * OUT_HW)        // 112 (b, oh) pairs
#define NPIX   (NB * OUT_HW * OUT_HW)

__device__ __forceinline__ int win_start(int o) { return (o * IN_HW) / OUT_HW; }
__device__ __forceinline__ int win_stop(int o)  { return ((o + 1) * IN_HW + OUT_HW - 1) / OUT_HW; }

__device__ __forceinline__ void f4add(float4& a, const float4& v) {
    a.x += v.x; a.y += v.y; a.z += v.z; a.w += v.w;
}

// window index per j (ow = (7*((tid>>4)+16j))>>9): constant K except crossing j's
__device__ __constant__ const int KJ_[1] = {0}; // (unused; tables are constexpr below)

__global__ __launch_bounds__(256)
void pool_stream_kernel(const float4* __restrict__ x, float4* __restrict__ partial) {
    // compile-time window tables for j = 0..31
    constexpr int KJ[32] = {0,0,0,0,0, 1,1,1,1,1, 2,2,2,2, 3,3,3,3,3,
                            4,4,4,4, 5,5,5,5,5, 6,6,6,6};
    constexpr int BJ[32] = {-1,-1,-1,-1, 9, -1,-1,-1,-1, 2, -1,-1,-1, 11,
                            -1,-1,-1,-1, 4, -1,-1,-1, 13, -1,-1,-1,-1, 6,
                            -1,-1,-1,-1};

    const int blk   = blockIdx.x;           // pair*NCHUNK + chunk
    const int chunk = blk % NCHUNK;
    const int pair  = blk / NCHUNK;         // b*7 + oh
    const int oh    = pair % OUT_HW;
    const int b     = pair / OUT_HW;

    const int hs = win_start(oh);
    const int r0 = hs + chunk * RPC;
    const int r1 = min(hs + (win_stop(oh) - hs), r0 + RPC);

    const int tid  = threadIdx.x;
    const int base = tid >> 4;              // w-residue group 0..15
    const int c4   = tid & 15;

    float4 acc[7];
    #pragma unroll
    for (int o = 0; o < 7; ++o) acc[o] = make_float4(0.f, 0.f, 0.f, 0.f);

    #pragma unroll 1
    for (int h = r0; h < r1; ++h) {
        const float4* seg = x + (size_t)(b * IN_HW + h) * (IN_HW * C4) + tid;
        #pragma unroll
        for (int j = 0; j < 32; ++j) {
            float4 v = seg[256 * j];
            const int K = KJ[j];
            const int B = BJ[j];
            if (B < 0) {
                f4add(acc[K], v);
            } else {
                if (base <= B) f4add(acc[K], v);     // w < stop(K)
                if (base >= B) f4add(acc[K + 1], v); // w >= start(K+1)
            }
        }
    }

    // reduce over the 16 base groups: lds[base][ow][c4]
    __shared__ float4 lds[16][7][16];       // 28 KB
    #pragma unroll
    for (int o = 0; o < 7; ++o) lds[base][o][c4] = acc[o];
    __syncthreads();

    if (tid < 7 * C4) {                     // tid = ow*16 + c4
        const int ow_ = tid >> 4;
        const int c_  = tid & 15;
        float4 s = make_float4(0.f, 0.f, 0.f, 0.f);
        #pragma unroll
        for (int g = 0; g < 16; ++g) f4add(s, lds[g][ow_][c_]);
        partial[((size_t)pair * NCHUNK + chunk) * (7 * C4) + tid] = s;
    }
}

// ---------------- finisher: sum chunks + scale ----------------
// total threads = NPAIR * 7 * C4 = 12544; out flat float4 idx == thread idx
__global__ __launch_bounds__(256)
void pool_finish_kernel(const float4* __restrict__ partial, float4* __restrict__ out) {
    const int idx = blockIdx.x * 256 + threadIdx.x;
    if (idx >= NPAIR * 7 * C4) return;

    const int t    = idx % (7 * C4);        // ow*16 + c4
    const int pair = idx / (7 * C4);
    const int ow   = t >> 4;
    const int oh   = pair % OUT_HW;

    float4 s = make_float4(0.f, 0.f, 0.f, 0.f);
    #pragma unroll
    for (int k = 0; k < NCHUNK; ++k) {
        float4 v = partial[((size_t)pair * NCHUNK + k) * (7 * C4) + t];
        f4add(s, v);
    }
    const float scale = 1.0f / (float)((win_stop(oh) - win_start(oh)) *
                                       (win_stop(ow) - win_start(ow)));
    s.x *= scale; s.y *= scale; s.z *= scale; s.w *= scale;
    out[idx] = s;
}

// ---------------- fallback: fused single kernel (if ws too small) ----------------
__global__ __launch_bounds__(256)
void pool_fused_kernel(const float4* __restrict__ x, float4* __restrict__ out) {
    __shared__ float4 red[256];

    const int blk = blockIdx.x;              // (b*7 + oh)*7 + ow
    const int ow = blk % OUT_HW;
    const int oh = (blk / OUT_HW) % OUT_HW;
    const int b  = blk / (OUT_HW * OUT_HW);

    const int tid = threadIdx.x;
    const int c4 = tid & 15;
    const int rg = tid >> 4;

    const int hs = win_start(oh), he = win_stop(oh);
    const int ws = win_start(ow), we = win_stop(ow);

    float4 acc = make_float4(0.f, 0.f, 0.f, 0.f);
    for (int h = hs + rg; h < he; h += 16) {
        const float4* row = x + ((size_t)(b * IN_HW + h)) * (IN_HW * C4);
        #pragma unroll 8
        for (int w = ws; w < we; ++w) {
            float4 v = row[w * C4 + c4];
            f4add(acc, v);
        }
    }
    red[tid] = acc;
    __syncthreads();

    #pragma unroll
    for (int s = 8; s >= 1; s >>= 1) {
        if (rg < s) {
            float4 o = red[(rg + s) * 16 + c4];
            f4add(o, red[rg * 16 + c4]);
            red[rg * 16 + c4] = o;
        }
        __syncthreads();
    }

    if (rg == 0) {
        const float scale = 1.0f / (float)((he - hs) * (we - ws));
        float4 m = red[c4];
        m.x *= scale; m.y *= scale; m.z *= scale; m.w *= scale;
        out[(size_t)blk * C4 + c4] = m;
    }
}

extern "C" void kernel_launch(void* const* d_in, const int* in_sizes, int n_in,
                              void* d_out, int out_size, void* d_ws, size_t ws_size,
                              hipStream_t stream) {
    const float4* x = (const float4*)d_in[0];
    float4* out = (float4*)d_out;

    const size_t ws_needed = (size_t)NPAIR * NCHUNK * 7 * C4 * sizeof(float4); // ~3.8 MB

    if (ws_size >= ws_needed) {
        float4* partial = (float4*)d_ws;
        pool_stream_kernel<<<NPAIR * NCHUNK, 256, 0, stream>>>(x, partial);
        pool_finish_kernel<<<(NPAIR * 7 * C4 + 255) / 256, 256, 0, stream>>>(partial, out);
    } else {
        pool_fused_kernel<<<NPIX, 256, 0, stream>>>(x, out);
    }
}

// Round 6
// 185.108 us; speedup vs baseline: 1.1509x; 1.0503x over previous
//
#include <hip/hip_runtime.h>

// Adaptive average pooling (16, 512, 512, 64) f32 -> (16, 7, 7, 64) f32.
// All 49 windows are 74x74 (overlap 1 row/col with neighbors).
//
// pool_stream: one block per (b, oh, 2-row chunk); 74 = 2*37 so all 37 chunks
// are equal -> 4144 uniform blocks. Block streams its 2 rows fully
// sequentially (thread tid reads float4 tid+256j; c4=tid&15 invariant,
// w = (tid>>4)+16j). For compile-time j the target window is a compile-time
// constant K except at 6 j's where a 16-lane-uniform predicate selects K vs
// K+1 (boundary lane feeds both -- the 1-col overlap). acc[7] registers,
// static indices only. LDS-reduce over 16 base groups -> 7x16 float4 partial.
// Finisher sums 37 chunks + scales. Non-temporal loads (stream-once data).

#define IN_HW  512
#define OUT_HW 7
#define NB     16
#define C4     16
#define RPC    2                    // rows per chunk (74 = 2*37, exact)
#define NCHUNK 37
#define NPAIR  (NB * OUT_HW)        // 112 (b, oh) pairs
#define NPIX   (NB * OUT_HW * OUT_HW)

typedef float fx4 __attribute__((ext_vector_type(4)));

__device__ __forceinline__ int win_start(int o) { return (o * IN_HW) / OUT_HW; }
__device__ __forceinline__ int win_stop(int o)  { return ((o + 1) * IN_HW + OUT_HW - 1) / OUT_HW; }

__device__ __forceinline__ void f4add(float4& a, const float4& v) {
    a.x += v.x; a.y += v.y; a.z += v.z; a.w += v.w;
}
__device__ __forceinline__ void f4addv(float4& a, const fx4& v) {
    a.x += v.x; a.y += v.y; a.z += v.z; a.w += v.w;
}

__global__ __launch_bounds__(256, 4)
void pool_stream_kernel(const float4* __restrict__ x, float4* __restrict__ partial) {
    // compile-time window tables for j = 0..31 (ow = (7*((tid>>4)+16j))>>9)
    constexpr int KJ[32] = {0,0,0,0,0, 1,1,1,1,1, 2,2,2,2, 3,3,3,3,3,
                            4,4,4,4, 5,5,5,5,5, 6,6,6,6};
    constexpr int BJ[32] = {-1,-1,-1,-1, 9, -1,-1,-1,-1, 2, -1,-1,-1, 11,
                            -1,-1,-1,-1, 4, -1,-1,-1, 13, -1,-1,-1,-1, 6,
                            -1,-1,-1,-1};

    const int blk   = blockIdx.x;           // pair*NCHUNK + chunk
    const int chunk = blk % NCHUNK;
    const int pair  = blk / NCHUNK;         // b*7 + oh
    const int oh    = pair % OUT_HW;
    const int b     = pair / OUT_HW;

    const int r0 = win_start(oh) + chunk * RPC;   // always RPC full rows

    const int tid  = threadIdx.x;
    const int base = tid >> 4;              // w-residue group 0..15
    const int c4   = tid & 15;

    float4 acc[7];
    #pragma unroll
    for (int o = 0; o < 7; ++o) acc[o] = make_float4(0.f, 0.f, 0.f, 0.f);

    #pragma unroll 1
    for (int h = r0; h < r0 + RPC; ++h) {
        const fx4* seg = (const fx4*)(x + (size_t)(b * IN_HW + h) * (IN_HW * C4) + tid);
        #pragma unroll
        for (int j = 0; j < 32; ++j) {
            fx4 v = __builtin_nontemporal_load(&seg[256 * j]);
            const int K = KJ[j];
            const int B = BJ[j];
            if (B < 0) {
                f4addv(acc[K], v);
            } else {
                if (base <= B) f4addv(acc[K], v);     // w < stop(K)
                if (base >= B) f4addv(acc[K + 1], v); // w >= start(K+1)
            }
        }
    }

    // reduce over the 16 base groups: lds[base][ow][c4]
    __shared__ float4 lds[16][7][16];       // 28 KB
    #pragma unroll
    for (int o = 0; o < 7; ++o) lds[base][o][c4] = acc[o];
    __syncthreads();

    if (tid < 7 * C4) {                     // tid = ow*16 + c4
        const int ow_ = tid >> 4;
        const int c_  = tid & 15;
        float4 s = make_float4(0.f, 0.f, 0.f, 0.f);
        #pragma unroll
        for (int g = 0; g < 16; ++g) f4add(s, lds[g][ow_][c_]);
        partial[((size_t)pair * NCHUNK + chunk) * (7 * C4) + tid] = s;
    }
}

// ---------------- finisher: sum chunks + scale ----------------
// total threads = NPAIR * 7 * C4 = 12544; out flat float4 idx == thread idx
__global__ __launch_bounds__(256)
void pool_finish_kernel(const float4* __restrict__ partial, float4* __restrict__ out) {
    const int idx = blockIdx.x * 256 + threadIdx.x;
    if (idx >= NPAIR * 7 * C4) return;

    const int t    = idx % (7 * C4);        // ow*16 + c4
    const int pair = idx / (7 * C4);
    const int ow   = t >> 4;
    const int oh   = pair % OUT_HW;

    float4 s = make_float4(0.f, 0.f, 0.f, 0.f);
    #pragma unroll 4
    for (int k = 0; k < NCHUNK; ++k) {
        float4 v = partial[((size_t)pair * NCHUNK + k) * (7 * C4) + t];
        f4add(s, v);
    }
    const float scale = 1.0f / (float)((win_stop(oh) - win_start(oh)) *
                                       (win_stop(ow) - win_start(ow)));
    s.x *= scale; s.y *= scale; s.z *= scale; s.w *= scale;
    out[idx] = s;
}

// ---------------- fallback: fused single kernel (if ws too small) ----------------
__global__ __launch_bounds__(256)
void pool_fused_kernel(const float4* __restrict__ x, float4* __restrict__ out) {
    __shared__ float4 red[256];

    const int blk = blockIdx.x;              // (b*7 + oh)*7 + ow
    const int ow = blk % OUT_HW;
    const int oh = (blk / OUT_HW) % OUT_HW;
    const int b  = blk / (OUT_HW * OUT_HW);

    const int tid = threadIdx.x;
    const int c4 = tid & 15;
    const int rg = tid >> 4;

    const int hs = win_start(oh), he = win_stop(oh);
    const int ws = win_start(ow), we = win_stop(ow);

    float4 acc = make_float4(0.f, 0.f, 0.f, 0.f);
    for (int h = hs + rg; h < he; h += 16) {
        const float4* row = x + ((size_t)(b * IN_HW + h)) * (IN_HW * C4);
        #pragma unroll 8
        for (int w = ws; w < we; ++w) {
            float4 v = row[w * C4 + c4];
            f4add(acc, v);
        }
    }
    red[tid] = acc;
    __syncthreads();

    #pragma unroll
    for (int s = 8; s >= 1; s >>= 1) {
        if (rg < s) {
            float4 o = red[(rg + s) * 16 + c4];
            f4add(o, red[rg * 16 + c4]);
            red[rg * 16 + c4] = o;
        }
        __syncthreads();
    }

    if (rg == 0) {
        const float scale = 1.0f / (float)((he - hs) * (we - ws));
        float4 m = red[c4];
        m.x *= scale; m.y *= scale; m.z *= scale; m.w *= scale;
        out[(size_t)blk * C4 + c4] = m;
    }
}

extern "C" void kernel_launch(void* const* d_in, const int* in_sizes, int n_in,
                              void* d_out, int out_size, void* d_ws, size_t ws_size,
                              hipStream_t stream) {
    const float4* x = (const float4*)d_in[0];
    float4* out = (float4*)d_out;

    const size_t ws_needed = (size_t)NPAIR * NCHUNK * 7 * C4 * sizeof(float4); // ~7.4 MB

    if (ws_size >= ws_needed) {
        float4* partial = (float4*)d_ws;
        pool_stream_kernel<<<NPAIR * NCHUNK, 256, 0, stream>>>(x, partial);
        pool_finish_kernel<<<(NPAIR * 7 * C4 + 255) / 256, 256, 0, stream>>>(partial, out);
    } else {
        pool_fused_kernel<<<NPIX, 256, 0, stream>>>(x, out);
    }
}

// Round 7
// 180.348 us; speedup vs baseline: 1.1813x; 1.0264x over previous
//
#include <hip/hip_runtime.h>

// Adaptive average pooling (16, 512, 512, 64) f32 -> (16, 7, 7, 64) f32.
// All 49 windows are exactly 74x74 (uniform scale 1/5476); h-windows overlap
// by 1 row at rows {73,146,219,292,365,438} (membership: oh in
// [(7r)>>9, (7r+6)>>9]), w-windows overlap by 1 col (handled by BJ table).
//
// Single pass: one block per (b, row-pair) -> 4096 uniform blocks, every
// input row streamed exactly once, fully sequentially (thread tid reads
// float4 tid+256j; c4=tid&15 invariant, w=(tid>>4)+16j; per-j window index
// is compile-time K except 6 j's with a 16-lane-uniform predicate, boundary
// lane feeding both windows). Per-row LDS reduce over 16 base groups, then
// 112 lanes unsafeAtomicAdd the scaled 7x16-float4 row-sum into d_out
// (200 KB, L2-resident, native global_atomic_add_f32). No finisher, no ws.

#define IN_HW  512
#define OUT_HW 7
#define NB     16
#define C4     16
#define NPIX   (NB * OUT_HW * OUT_HW)   // 784

typedef float fx4 __attribute__((ext_vector_type(4)));

__device__ __forceinline__ void f4add(float4& a, const float4& v) {
    a.x += v.x; a.y += v.y; a.z += v.z; a.w += v.w;
}
__device__ __forceinline__ void f4addv(float4& a, const fx4& v) {
    a.x += v.x; a.y += v.y; a.z += v.z; a.w += v.w;
}

// ---------------- zero d_out (re-run every call; replays don't re-poison) ----
__global__ __launch_bounds__(256)
void pool_zero_kernel(float4* __restrict__ out) {
    const int idx = blockIdx.x * 256 + threadIdx.x;
    if (idx < NPIX * C4) out[idx] = make_float4(0.f, 0.f, 0.f, 0.f);
}

// ---------------- main: stream + atomic accumulate ----------------
// grid.x = NB * 256 (4096), block = 256
__global__ __launch_bounds__(256, 4)
void pool_stream_atomic_kernel(const float4* __restrict__ x, float* __restrict__ out) {
    // compile-time window tables for j = 0..31 (ow of w=(tid>>4)+16j)
    constexpr int KJ[32] = {0,0,0,0,0, 1,1,1,1,1, 2,2,2,2, 3,3,3,3,3,
                            4,4,4,4, 5,5,5,5,5, 6,6,6,6};
    constexpr int BJ[32] = {-1,-1,-1,-1, 9, -1,-1,-1,-1, 2, -1,-1,-1, 11,
                            -1,-1,-1,-1, 4, -1,-1,-1, 13, -1,-1,-1,-1, 6,
                            -1,-1,-1,-1};
    constexpr float SCALE = 1.0f / (74.0f * 74.0f);

    const int blk = blockIdx.x;             // b*256 + row-pair
    const int rp  = blk & 255;
    const int b   = blk >> 8;

    const int tid  = threadIdx.x;
    const int base = tid >> 4;              // w-residue group 0..15
    const int c4   = tid & 15;

    __shared__ float4 lds[16][7][16];       // 28 KB

    #pragma unroll
    for (int rr = 0; rr < 2; ++rr) {
        const int r = rp * 2 + rr;

        float4 acc[7];
        #pragma unroll
        for (int o = 0; o < 7; ++o) acc[o] = make_float4(0.f, 0.f, 0.f, 0.f);

        const fx4* seg = (const fx4*)(x + (size_t)(b * IN_HW + r) * (IN_HW * C4) + tid);
        #pragma unroll
        for (int j = 0; j < 32; ++j) {
            fx4 v = __builtin_nontemporal_load(&seg[256 * j]);
            const int K = KJ[j];
            const int B = BJ[j];
            if (B < 0) {
                f4addv(acc[K], v);
            } else {
                if (base <= B) f4addv(acc[K], v);     // w < stop(K)
                if (base >= B) f4addv(acc[K + 1], v); // w >= start(K+1)
            }
        }

        #pragma unroll
        for (int o = 0; o < 7; ++o) lds[base][o][c4] = acc[o];
        __syncthreads();

        if (tid < 7 * C4) {                 // tid = ow*16 + c
            const int ow_ = tid >> 4;
            const int c_  = tid & 15;
            float4 s = make_float4(0.f, 0.f, 0.f, 0.f);
            #pragma unroll
            for (int g = 0; g < 16; ++g) f4add(s, lds[g][ow_][c_]);
            s.x *= SCALE; s.y *= SCALE; s.z *= SCALE; s.w *= SCALE;

            const int oh_lo = (7 * r) >> 9;
            const int oh_hi = (7 * r + 6) >> 9;
            for (int oh = oh_lo; oh <= oh_hi; ++oh) {
                float* dst = out + ((((size_t)b * OUT_HW + oh) * OUT_HW + ow_) * C4 + c_) * 4;
                unsafeAtomicAdd(dst + 0, s.x);
                unsafeAtomicAdd(dst + 1, s.y);
                unsafeAtomicAdd(dst + 2, s.z);
                unsafeAtomicAdd(dst + 3, s.w);
            }
        }
        __syncthreads();                    // lds reused by next row
    }
}

extern "C" void kernel_launch(void* const* d_in, const int* in_sizes, int n_in,
                              void* d_out, int out_size, void* d_ws, size_t ws_size,
                              hipStream_t stream) {
    const float4* x = (const float4*)d_in[0];

    pool_zero_kernel<<<(NPIX * C4 + 255) / 256, 256, 0, stream>>>((float4*)d_out);
    pool_stream_atomic_kernel<<<NB * 256, 256, 0, stream>>>(x, (float*)d_out);
}

// Round 8
// 176.583 us; speedup vs baseline: 1.2065x; 1.0213x over previous
//
#include <hip/hip_runtime.h>

// Adaptive average pooling (16, 512, 512, 64) f32 -> (16, 7, 7, 64) f32.
// All 49 windows are exactly 74x74 (uniform scale 1/5476); h-windows overlap
// by 1 row at rows {73,146,219,292,365,438} (membership: oh in
// [(7r)>>9, (7r+6)>>9]), w-windows overlap by 1 col (handled by BJ table).
//
// Single pass: one block per (b, row-pair) -> 4096 uniform blocks, every
// input row streamed exactly once, fully sequentially (thread tid reads
// float4 tid+256j; c4=tid&15 invariant, w=(tid>>4)+16j; per-j window index
// is compile-time K except 6 j's with a 16-lane-uniform predicate, boundary
// lane feeding both windows). 250/256 row-pairs have both rows in the same
// single oh-window -> fuse both rows into one accumulate + ONE LDS flush +
// ONE set of atomics (halves flush overhead); 6 straddling pairs/image take
// the per-row path. 112 lanes unsafeAtomicAdd scaled sums into d_out
// (200 KB, L2-resident). No finisher, no workspace.

#define IN_HW  512
#define OUT_HW 7
#define NB     16
#define C4     16
#define NPIX   (NB * OUT_HW * OUT_HW)   // 784

typedef float fx4 __attribute__((ext_vector_type(4)));

__device__ __forceinline__ void f4add(float4& a, const float4& v) {
    a.x += v.x; a.y += v.y; a.z += v.z; a.w += v.w;
}
__device__ __forceinline__ void f4addv(float4& a, const fx4& v) {
    a.x += v.x; a.y += v.y; a.z += v.z; a.w += v.w;
}

// compile-time window tables for j = 0..31 (ow of w=(tid>>4)+16j)
__device__ constexpr int KJ[32] = {0,0,0,0,0, 1,1,1,1,1, 2,2,2,2, 3,3,3,3,3,
                                   4,4,4,4, 5,5,5,5,5, 6,6,6,6};
__device__ constexpr int BJ[32] = {-1,-1,-1,-1, 9, -1,-1,-1,-1, 2, -1,-1,-1, 11,
                                   -1,-1,-1,-1, 4, -1,-1,-1, 13, -1,-1,-1,-1, 6,
                                   -1,-1,-1,-1};

__device__ __forceinline__ void accum_row(float4 (&acc)[7], const float4* __restrict__ x,
                                          int b, int h, int tid, int base) {
    const fx4* seg = (const fx4*)(x + (size_t)(b * IN_HW + h) * (IN_HW * C4) + tid);
    #pragma unroll
    for (int j = 0; j < 32; ++j) {
        fx4 v = __builtin_nontemporal_load(&seg[256 * j]);
        const int K = KJ[j];
        const int B = BJ[j];
        if (B < 0) {
            f4addv(acc[K], v);
        } else {
            if (base <= B) f4addv(acc[K], v);     // w < stop(K)
            if (base >= B) f4addv(acc[K + 1], v); // w >= start(K+1)
        }
    }
}

// ---------------- zero d_out (re-run every call; replays don't re-poison) ----
__global__ __launch_bounds__(256)
void pool_zero_kernel(float4* __restrict__ out) {
    const int idx = blockIdx.x * 256 + threadIdx.x;
    if (idx < NPIX * C4) out[idx] = make_float4(0.f, 0.f, 0.f, 0.f);
}

// ---------------- main: stream + atomic accumulate ----------------
// grid.x = NB * 256 (4096), block = 256
__global__ __launch_bounds__(256, 4)
void pool_stream_atomic_kernel(const float4* __restrict__ x, float* __restrict__ out) {
    constexpr float SCALE = 1.0f / (74.0f * 74.0f);

    const int blk = blockIdx.x;             // b*256 + row-pair
    const int rp  = blk & 255;
    const int b   = blk >> 8;
    const int r0  = rp * 2;

    const int tid  = threadIdx.x;
    const int base = tid >> 4;              // w-residue group 0..15
    const int c4   = tid & 15;

    __shared__ float4 lds[16][7][16];       // 28 KB

    // oh membership of the two rows
    const int lo0 = (7 * r0) >> 9,       hi0 = (7 * r0 + 6) >> 9;
    const int lo1 = (7 * r0 + 7) >> 9,   hi1 = (7 * r0 + 13) >> 9;
    const bool fused = (lo0 == hi0) & (lo1 == hi1) & (lo0 == lo1);

    float4 acc[7];

    if (fused) {
        #pragma unroll
        for (int o = 0; o < 7; ++o) acc[o] = make_float4(0.f, 0.f, 0.f, 0.f);
        #pragma unroll 1
        for (int h = r0; h < r0 + 2; ++h) accum_row(acc, x, b, h, tid, base);

        #pragma unroll
        for (int o = 0; o < 7; ++o) lds[base][o][c4] = acc[o];
        __syncthreads();

        if (tid < 7 * C4) {                 // tid = ow*16 + c
            const int ow_ = tid >> 4;
            const int c_  = tid & 15;
            float4 s = make_float4(0.f, 0.f, 0.f, 0.f);
            #pragma unroll
            for (int g = 0; g < 16; ++g) f4add(s, lds[g][ow_][c_]);
            s.x *= SCALE; s.y *= SCALE; s.z *= SCALE; s.w *= SCALE;

            float* dst = out + ((((size_t)b * OUT_HW + lo0) * OUT_HW + ow_) * C4 + c_) * 4;
            unsafeAtomicAdd(dst + 0, s.x);
            unsafeAtomicAdd(dst + 1, s.y);
            unsafeAtomicAdd(dst + 2, s.z);
            unsafeAtomicAdd(dst + 3, s.w);
        }
    } else {
        #pragma unroll 1
        for (int rr = 0; rr < 2; ++rr) {
            const int r = r0 + rr;

            #pragma unroll
            for (int o = 0; o < 7; ++o) acc[o] = make_float4(0.f, 0.f, 0.f, 0.f);
            accum_row(acc, x, b, r, tid, base);

            #pragma unroll
            for (int o = 0; o < 7; ++o) lds[base][o][c4] = acc[o];
            __syncthreads();

            if (tid < 7 * C4) {
                const int ow_ = tid >> 4;
                const int c_  = tid & 15;
                float4 s = make_float4(0.f, 0.f, 0.f, 0.f);
                #pragma unroll
                for (int g = 0; g < 16; ++g) f4add(s, lds[g][ow_][c_]);
                s.x *= SCALE; s.y *= SCALE; s.z *= SCALE; s.w *= SCALE;

                const int oh_lo = (7 * r) >> 9;
                const int oh_hi = (7 * r + 6) >> 9;
                for (int oh = oh_lo; oh <= oh_hi; ++oh) {
                    float* dst = out + ((((size_t)b * OUT_HW + oh) * OUT_HW + ow_) * C4 + c_) * 4;
                    unsafeAtomicAdd(dst + 0, s.x);
                    unsafeAtomicAdd(dst + 1, s.y);
                    unsafeAtomicAdd(dst + 2, s.z);
                    unsafeAtomicAdd(dst + 3, s.w);
                }
            }
            __syncthreads();                // lds reused by next row
        }
    }
}

extern "C" void kernel_launch(void* const* d_in, const int* in_sizes, int n_in,
                              void* d_out, int out_size, void* d_ws, size_t ws_size,
                              hipStream_t stream) {
    const float4* x = (const float4*)d_in[0];

    pool_zero_kernel<<<(NPIX * C4 + 255) / 256, 256, 0, stream>>>((float4*)d_out);
    pool_stream_atomic_kernel<<<NB * 256, 256, 0, stream>>>(x, (float*)d_out);
}

// Round 9
// 175.706 us; speedup vs baseline: 1.2125x; 1.0050x over previous
//
#include <hip/hip_runtime.h>

// Adaptive average pooling (16, 512, 512, 64) f32 -> (16, 7, 7, 64) f32.
// All 49 windows are exactly 74x74 (uniform scale 1/5476); h-windows overlap
// by 1 row at rows {73,146,219,292,365,438} (membership: oh in
// [(7r)>>9, (7r+6)>>9]), w-windows overlap by 1 col (handled by BJ table).
//
// Single pass: one block per (b, row-pair) -> 4096 uniform blocks, every
// input row streamed exactly once, fully sequentially (thread tid reads
// float4 tid+256j; c4=tid&15 invariant, w=(tid>>4)+16j; per-j window index
// is compile-time K except 6 j's with a 16-lane-uniform predicate, boundary
// lane feeding both windows). 250/256 row-pairs have both rows in the same
// single oh-window -> fuse both rows into one accumulate + ONE LDS flush +
// ONE set of atomics; 6 straddling pairs/image take the per-row path.
// 112 lanes unsafeAtomicAdd scaled sums into d_out (200 KB, L2-resident).
// d_out zeroed via hipMemsetAsync (graph-capturable; replays don't re-poison).

#define IN_HW  512
#define OUT_HW 7
#define NB     16
#define C4     16
#define NPIX   (NB * OUT_HW * OUT_HW)   // 784

typedef float fx4 __attribute__((ext_vector_type(4)));

__device__ __forceinline__ void f4add(float4& a, const float4& v) {
    a.x += v.x; a.y += v.y; a.z += v.z; a.w += v.w;
}
__device__ __forceinline__ void f4addv(float4& a, const fx4& v) {
    a.x += v.x; a.y += v.y; a.z += v.z; a.w += v.w;
}

// compile-time window tables for j = 0..31 (ow of w=(tid>>4)+16j)
__device__ constexpr int KJ[32] = {0,0,0,0,0, 1,1,1,1,1, 2,2,2,2, 3,3,3,3,3,
                                   4,4,4,4, 5,5,5,5,5, 6,6,6,6};
__device__ constexpr int BJ[32] = {-1,-1,-1,-1, 9, -1,-1,-1,-1, 2, -1,-1,-1, 11,
                                   -1,-1,-1,-1, 4, -1,-1,-1, 13, -1,-1,-1,-1, 6,
                                   -1,-1,-1,-1};

__device__ __forceinline__ void accum_row(float4 (&acc)[7], const float4* __restrict__ x,
                                          int b, int h, int tid, int base) {
    const fx4* seg = (const fx4*)(x + (size_t)(b * IN_HW + h) * (IN_HW * C4) + tid);
    #pragma unroll
    for (int j = 0; j < 32; ++j) {
        fx4 v = __builtin_nontemporal_load(&seg[256 * j]);
        const int K = KJ[j];
        const int B = BJ[j];
        if (B < 0) {
            f4addv(acc[K], v);
        } else {
            if (base <= B) f4addv(acc[K], v);     // w < stop(K)
            if (base >= B) f4addv(acc[K + 1], v); // w >= start(K+1)
        }
    }
}

// ---------------- main: stream + atomic accumulate ----------------
// grid.x = NB * 256 (4096), block = 256
__global__ __launch_bounds__(256, 4)
void pool_stream_atomic_kernel(const float4* __restrict__ x, float* __restrict__ out) {
    constexpr float SCALE = 1.0f / (74.0f * 74.0f);

    const int blk = blockIdx.x;             // b*256 + row-pair
    const int rp  = blk & 255;
    const int b   = blk >> 8;
    const int r0  = rp * 2;

    const int tid  = threadIdx.x;
    const int base = tid >> 4;              // w-residue group 0..15
    const int c4   = tid & 15;

    __shared__ float4 lds[16][7][16];       // 28 KB

    // oh membership of the two rows
    const int lo0 = (7 * r0) >> 9,       hi0 = (7 * r0 + 6) >> 9;
    const int lo1 = (7 * r0 + 7) >> 9,   hi1 = (7 * r0 + 13) >> 9;
    const bool fused = (lo0 == hi0) & (lo1 == hi1) & (lo0 == lo1);

    float4 acc[7];

    if (fused) {
        #pragma unroll
        for (int o = 0; o < 7; ++o) acc[o] = make_float4(0.f, 0.f, 0.f, 0.f);
        #pragma unroll 1
        for (int h = r0; h < r0 + 2; ++h) accum_row(acc, x, b, h, tid, base);

        #pragma unroll
        for (int o = 0; o < 7; ++o) lds[base][o][c4] = acc[o];
        __syncthreads();

        if (tid < 7 * C4) {                 // tid = ow*16 + c
            const int ow_ = tid >> 4;
            const int c_  = tid & 15;
            float4 s = make_float4(0.f, 0.f, 0.f, 0.f);
            #pragma unroll
            for (int g = 0; g < 16; ++g) f4add(s, lds[g][ow_][c_]);
            s.x *= SCALE; s.y *= SCALE; s.z *= SCALE; s.w *= SCALE;

            float* dst = out + ((((size_t)b * OUT_HW + lo0) * OUT_HW + ow_) * C4 + c_) * 4;
            unsafeAtomicAdd(dst + 0, s.x);
            unsafeAtomicAdd(dst + 1, s.y);
            unsafeAtomicAdd(dst + 2, s.z);
            unsafeAtomicAdd(dst + 3, s.w);
        }
    } else {
        #pragma unroll 1
        for (int rr = 0; rr < 2; ++rr) {
            const int r = r0 + rr;

            #pragma unroll
            for (int o = 0; o < 7; ++o) acc[o] = make_float4(0.f, 0.f, 0.f, 0.f);
            accum_row(acc, x, b, r, tid, base);

            #pragma unroll
            for (int o = 0; o < 7; ++o) lds[base][o][c4] = acc[o];
            __syncthreads();

            if (tid < 7 * C4) {
                const int ow_ = tid >> 4;
                const int c_  = tid & 15;
                float4 s = make_float4(0.f, 0.f, 0.f, 0.f);
                #pragma unroll
                for (int g = 0; g < 16; ++g) f4add(s, lds[g][ow_][c_]);
                s.x *= SCALE; s.y *= SCALE; s.z *= SCALE; s.w *= SCALE;

                const int oh_lo = (7 * r) >> 9;
                const int oh_hi = (7 * r + 6) >> 9;
                for (int oh = oh_lo; oh <= oh_hi; ++oh) {
                    float* dst = out + ((((size_t)b * OUT_HW + oh) * OUT_HW + ow_) * C4 + c_) * 4;
                    unsafeAtomicAdd(dst + 0, s.x);
                    unsafeAtomicAdd(dst + 1, s.y);
                    unsafeAtomicAdd(dst + 2, s.z);
                    unsafeAtomicAdd(dst + 3, s.w);
                }
            }
            __syncthreads();                // lds reused by next row
        }
    }
}

extern "C" void kernel_launch(void* const* d_in, const int* in_sizes, int n_in,
                              void* d_out, int out_size, void* d_ws, size_t ws_size,
                              hipStream_t stream) {
    const float4* x = (const float4*)d_in[0];

    // zero the accumulation target every call (graph-capturable async memset)
    hipMemsetAsync(d_out, 0, (size_t)NPIX * C4 * sizeof(float4), stream);
    pool_stream_atomic_kernel<<<NB * 256, 256, 0, stream>>>(x, (float*)d_out);
}